// Round 17
// baseline (426.323 us; speedup 1.0000x reference)
//
#include <hip/hip_runtime.h>
#include <hip/hip_bf16.h>

// R-GCN layer (fp32 in/out): out = relu(agg0/deg0 @ W0 + agg1/deg1 @ W1 + x @ Wl + b)
// Round 23: r21 champion (333.0us) + two bin tweaks:
//  (1) CH2 4096->8192: write runs 1.3->2.6 edges (halved write-allocate amp),
//      reserve atomics halved; 391 bin blocks still > 256 CUs so the striped
//      reserve keeps chains short (parallelism penalty of r14/r16 gone).
//  (2) binned pass-2 stores are nontemporal (written once, read once next
//      kernel) -> less L2/L3 eviction of xb, agg's gather working set.
// Fusion abandoned: r17/r22 both capped at Occ ~34% by barrier-phase
// serialization (~+70us), exceeding the ~25us/launch gap it saves.
//
// ws: wb ushort[12*8*64*8] | binned uint[NB*CAPB] | xb bf16[(N+1)*128] |
//     aggb bf16[2N*128] | cursor int[8*NB]
// Requires N <= 131072 (src packed into 17 bits).

#define DFEAT 128
#define CH2 8192         // edges per bin block -> nbin=391
#define PSH 6            // bucket = 64 dst nodes
#define NBMAX 3200       // max buckets = ceil(2N/64)
#define KSUB 8           // reserve stripes per bucket
#define CAPS 192         // capacity per (bucket,stripe): mean 128, +5.7 sigma
#define CAPB 1536        // = KSUB*CAPS, LDS CSR capacity per bucket
#define NPACK 24         // pack_b blocks

typedef __attribute__((ext_vector_type(8))) short short8v;       // 8 bf16 (4 VGPRs)
typedef __attribute__((ext_vector_type(4))) float float4v;       // 4 fp32
typedef __attribute__((ext_vector_type(2))) unsigned int u2v;    // 8B
typedef __attribute__((ext_vector_type(4))) unsigned short ushort4v;

// Fused front: blocks [0,nbin) bin edges into striped bucket regions,
// [nbin,nbin+NPACK) pack W into MFMA B-fragment order, rest convert x->bf16.
__global__ __launch_bounds__(256) void front_kernel(
        const float4v* __restrict__ x4, ushort4v* __restrict__ xb4, int n4,
        const int* __restrict__ src0, const int* __restrict__ dst0,
        const int* __restrict__ src1, const int* __restrict__ dst1,
        int* __restrict__ cursor, unsigned* __restrict__ binned,
        const float* __restrict__ wrel, const float* __restrict__ wloop,
        unsigned short* __restrict__ wb,
        int N, int E, int NB, int nbin) {
    __shared__ unsigned cntp[NBMAX / 2];   // packed ushort-pair counts (6.4KB)
    __shared__ int base[NBMAX];            // 12.8KB
    int tid = threadIdx.x;
    int bid = blockIdx.x;

    if (bid < nbin) {
        // ---- bin section: block-staged counting scatter, striped reserve ----
        auto ldp = [&](int i) {            // bucket-space dst id p = r*N + t
            int r = (i >= E) ? 1 : 0;
            int e = i - r * E;
            int t = r ? dst1[e] : dst0[e];
            return r * N + t;
        };
        auto lds_ = [&](int i) {           // src node
            int r = (i >= E) ? 1 : 0;
            int e = i - r * E;
            return r ? src1[e] : src0[e];
        };
        int k = bid & (KSUB - 1);
        for (int i = tid; i < NBMAX / 2; i += 256) cntp[i] = 0;
        __syncthreads();
        int lo = bid * CH2, hi = min(2 * E, lo + CH2);
        // pass 1: local histogram, 4 independent loads per iteration
        for (int ii = lo + tid; ii < hi; ii += 1024) {
            int p0 = ldp(ii);
            int p1 = (ii + 256 < hi) ? ldp(ii + 256) : -1;
            int p2 = (ii + 512 < hi) ? ldp(ii + 512) : -1;
            int p3 = (ii + 768 < hi) ? ldp(ii + 768) : -1;
            int b0 = p0 >> PSH;
            atomicAdd(&cntp[b0 >> 1], (b0 & 1) ? 0x10000u : 1u);
            if (p1 >= 0) { int b1 = p1 >> PSH; atomicAdd(&cntp[b1 >> 1], (b1 & 1) ? 0x10000u : 1u); }
            if (p2 >= 0) { int b2 = p2 >> PSH; atomicAdd(&cntp[b2 >> 1], (b2 & 1) ? 0x10000u : 1u); }
            if (p3 >= 0) { int b3 = p3 >> PSH; atomicAdd(&cntp[b3 >> 1], (b3 & 1) ? 0x10000u : 1u); }
        }
        __syncthreads();
        // bulk-reserve one contiguous run per (block,bucket) in stripe k
        for (int b = tid; b < NBMAX; b += 256) {
            int c = (int)((cntp[b >> 1] >> ((b & 1) * 16)) & 0xFFFFu);
            if (c) base[b] = b * CAPB + k * CAPS + atomicAdd(&cursor[k * NB + b], c);
        }
        __syncthreads();
        // pass 2: scatter into runs; 4 independent edge loads per iteration;
        // nontemporal stores (binned is written once, read once)
        for (int ii = lo + tid; ii < hi; ii += 1024) {
            int p0 = ldp(ii);             int s0 = lds_(ii);
            int i1 = ii + 256, i2 = ii + 512, i3 = ii + 768;
            int p1 = (i1 < hi) ? ldp(i1) : -1;  int s1 = (i1 < hi) ? lds_(i1) : 0;
            int p2 = (i2 < hi) ? ldp(i2) : -1;  int s2 = (i2 < hi) ? lds_(i2) : 0;
            int p3 = (i3 < hi) ? ldp(i3) : -1;  int s3 = (i3 < hi) ? lds_(i3) : 0;
            { int slot = atomicAdd(&base[p0 >> PSH], 1);
              __builtin_nontemporal_store(
                  ((unsigned)(p0 & 63) << 17) | (unsigned)s0, binned + slot); }
            if (p1 >= 0) { int slot = atomicAdd(&base[p1 >> PSH], 1);
                           __builtin_nontemporal_store(
                               ((unsigned)(p1 & 63) << 17) | (unsigned)s1, binned + slot); }
            if (p2 >= 0) { int slot = atomicAdd(&base[p2 >> PSH], 1);
                           __builtin_nontemporal_store(
                               ((unsigned)(p2 & 63) << 17) | (unsigned)s2, binned + slot); }
            if (p3 >= 0) { int slot = atomicAdd(&base[p3 >> PSH], 1);
                           __builtin_nontemporal_store(
                               ((unsigned)(p3 & 63) << 17) | (unsigned)s3, binned + slot); }
        }
    } else if (bid < nbin + NPACK) {
        // ---- pack_b section ----
        int t = (bid - nbin) * 256 + tid;    // 0..6143
        if (t < 12 * 8 * 64) {
            int lane = t & 63;
            int kbase = (t >> 9) * 32 + (lane >> 4) * 8;
            int col = (((t >> 6) & 7) << 4) + (lane & 15);
            unsigned short tmp[8];
#pragma unroll
            for (int j = 0; j < 8; ++j) {
                int kk = kbase + j;
                float v = (kk < 256) ? wrel[kk * DFEAT + col]
                                     : wloop[(kk - 256) * DFEAT + col];
                tmp[j] = __hip_bfloat16_raw(__float2bfloat16(v)).x;
            }
            *(ushort4*)(wb + t * 8)     = make_ushort4(tmp[0], tmp[1], tmp[2], tmp[3]);
            *(ushort4*)(wb + t * 8 + 4) = make_ushort4(tmp[4], tmp[5], tmp[6], tmp[7]);
        }
    } else {
        // ---- convert section: 4 coalesced float4 per thread (64B) ----
        int cb = bid - nbin - NPACK;
#pragma unroll
        for (int kk = 0; kk < 4; ++kk) {
            int i = cb * 1024 + kk * 256 + tid;
            if (i < n4) {
                float4v v = __builtin_nontemporal_load(x4 + i);
                ushort4v o;
                o[0] = __hip_bfloat16_raw(__float2bfloat16(v[0])).x;
                o[1] = __hip_bfloat16_raw(__float2bfloat16(v[1])).x;
                o[2] = __hip_bfloat16_raw(__float2bfloat16(v[2])).x;
                o[3] = __hip_bfloat16_raw(__float2bfloat16(v[3])).x;
                xb4[i] = o;
            }
        }
    }
}

#define CONSUME(Q0, Q1, Q2, Q3) {                                              \
    a[0] += __uint_as_float(Q0[0] << 16) + __uint_as_float(Q1[0] << 16)        \
          + __uint_as_float(Q2[0] << 16) + __uint_as_float(Q3[0] << 16);       \
    a[1] += __uint_as_float(Q0[0] & 0xffff0000u) + __uint_as_float(Q1[0] & 0xffff0000u) \
          + __uint_as_float(Q2[0] & 0xffff0000u) + __uint_as_float(Q3[0] & 0xffff0000u); \
    a[2] += __uint_as_float(Q0[1] << 16) + __uint_as_float(Q1[1] << 16)        \
          + __uint_as_float(Q2[1] << 16) + __uint_as_float(Q3[1] << 16);       \
    a[3] += __uint_as_float(Q0[1] & 0xffff0000u) + __uint_as_float(Q1[1] & 0xffff0000u) \
          + __uint_as_float(Q2[1] & 0xffff0000u) + __uint_as_float(Q3[1] & 0xffff0000u); }

// One 128-thread block per bucket (64 p's). CSR built in LDS from the 8
// striped sub-segments via a FLAT predicated 12-iteration loop, then one
// half-wave per p: 16 p's per half-wave, depth-3 rolling gather pipeline.
__global__ __launch_bounds__(128) void agg_kernel(
        const u2v* __restrict__ xb2,          // x bf16 rows as u2v[N][32]
        const unsigned* __restrict__ binned,
        const int* __restrict__ cursor,
        unsigned short* __restrict__ aggb, int N, int M, int NB) {
    __shared__ unsigned ebuf[CAPB];
    __shared__ int cnt[64], cur[64], rs[64];
    __shared__ int scnt[KSUB];
    int tid = threadIdx.x;
    int b = blockIdx.x;
    int P0 = b << PSH;
    int hw = tid >> 5, lane = tid & 31;   // 4 half-waves
    const unsigned* seg = binned + (size_t)b * CAPB;

    if (tid < 64) cnt[tid] = 0;
    if (tid < KSUB) scnt[tid] = min(cursor[tid * NB + b], CAPS);
    __syncthreads();
    // hist: flat predicated loop over the 8 sub-segments (12 iterations)
    for (int i = tid; i < CAPB; i += 128) {
        int k = (i * 683) >> 17;          // i / 192
        if (i - k * CAPS < scnt[k])
            atomicAdd(&cnt[seg[i] >> 17], 1);
    }
    __syncthreads();
    if (tid < 64) {
        int c = cnt[tid];
        int inc = c;
#pragma unroll
        for (int off = 1; off < 64; off <<= 1) {
            int t2 = __shfl_up(inc, off);
            if (tid >= off) inc += t2;
        }
        rs[tid] = inc - c;
        cur[tid] = inc - c;
    }
    __syncthreads();
    // counting-scatter into LDS CSR (same flat predicated loop)
    for (int i = tid; i < CAPB; i += 128) {
        int k = (i * 683) >> 17;
        if (i - k * CAPS < scnt[k]) {
            unsigned v = seg[i];
            int slot = atomicAdd(&cur[v >> 17], 1);
            ebuf[slot] = v & 0x1FFFFu;    // pre-masked src row index
        }
    }
    __syncthreads();

    for (int pi = 0; pi < 16; ++pi) {
        int pl = hw * 16 + pi;
        int s0 = rs[pl], c = cnt[pl];
        float4v a = (float4v){0.f, 0.f, 0.f, 0.f};
        int e = 0;
        if (c >= 8) {
            // prologue: load groups 0 and 1 (8 rows in flight)
            u2v A0 = xb2[(size_t)ebuf[s0]     * 32 + lane];
            u2v B0 = xb2[(size_t)ebuf[s0 + 1] * 32 + lane];
            u2v C0 = xb2[(size_t)ebuf[s0 + 2] * 32 + lane];
            u2v D0 = xb2[(size_t)ebuf[s0 + 3] * 32 + lane];
            u2v A1 = xb2[(size_t)ebuf[s0 + 4] * 32 + lane];
            u2v B1 = xb2[(size_t)ebuf[s0 + 5] * 32 + lane];
            u2v C1 = xb2[(size_t)ebuf[s0 + 6] * 32 + lane];
            u2v D1 = xb2[(size_t)ebuf[s0 + 7] * 32 + lane];
            // steady state: issue group e, consume group e-8
            for (e = 8; e + 4 <= c; e += 4) {
                u2v nA = xb2[(size_t)ebuf[s0 + e]     * 32 + lane];
                u2v nB = xb2[(size_t)ebuf[s0 + e + 1] * 32 + lane];
                u2v nC = xb2[(size_t)ebuf[s0 + e + 2] * 32 + lane];
                u2v nD = xb2[(size_t)ebuf[s0 + e + 3] * 32 + lane];
                CONSUME(A0, B0, C0, D0);
                A0 = A1; B0 = B1; C0 = C1; D0 = D1;
                A1 = nA; B1 = nB; C1 = nC; D1 = nD;
            }
            // epilogue: consume the two pending groups
            CONSUME(A0, B0, C0, D0);
            CONSUME(A1, B1, C1, D1);
        } else if (c >= 4) {
            u2v A0 = xb2[(size_t)ebuf[s0]     * 32 + lane];
            u2v B0 = xb2[(size_t)ebuf[s0 + 1] * 32 + lane];
            u2v C0 = xb2[(size_t)ebuf[s0 + 2] * 32 + lane];
            u2v D0 = xb2[(size_t)ebuf[s0 + 3] * 32 + lane];
            CONSUME(A0, B0, C0, D0);
            e = 4;
        }
        for (; e < c; ++e) {
            int s = ebuf[s0 + e];
            u2v g = xb2[(size_t)s * 32 + lane];
            a[0] += __uint_as_float(g[0] << 16);
            a[1] += __uint_as_float(g[0] & 0xffff0000u);
            a[2] += __uint_as_float(g[1] << 16);
            a[3] += __uint_as_float(g[1] & 0xffff0000u);
        }
        int pg = P0 + pl;
        if (pg < M) {
            float inv = 1.0f / (float)max(c, 1);
            ushort4v w;
            w[0] = __hip_bfloat16_raw(__float2bfloat16(a[0] * inv)).x;
            w[1] = __hip_bfloat16_raw(__float2bfloat16(a[1] * inv)).x;
            w[2] = __hip_bfloat16_raw(__float2bfloat16(a[2] * inv)).x;
            w[3] = __hip_bfloat16_raw(__float2bfloat16(a[3] * inv)).x;
            __builtin_nontemporal_store(
                w, (ushort4v*)(aggb + (size_t)pg * DFEAT + 4 * lane));
        }
    }
}

// MFMA GEMM (r15 version): out[row,col] = relu(sum_k A[row,k]*B[k,col]+b[col]),
// A row = [aggb[row] | aggb[N+row] | xb[row]] (bf16), B pre-packed (wb).
__global__ __launch_bounds__(256) void mfma_gemm_kernel(
        const unsigned short* __restrict__ aggb,
        const unsigned short* __restrict__ xb,
        const unsigned short* __restrict__ wb,
        const float* __restrict__ bias,
        float* __restrict__ out, int N) {
    int tid = threadIdx.x;
    int wv = tid >> 6, lane = tid & 63;
    int R0 = blockIdx.x * 128 + wv * 32;
    int mrow = lane & 15, quad = lane >> 4;

    float4v acc[2][8];
#pragma unroll
    for (int rt = 0; rt < 2; ++rt)
#pragma unroll
        for (int ct = 0; ct < 8; ++ct) acc[rt][ct] = (float4v){0.f, 0.f, 0.f, 0.f};

    int n0 = min(R0 + mrow, N - 1);
    int n1 = min(R0 + 16 + mrow, N - 1);

#pragma unroll
    for (int kc = 0; kc < 12; ++kc) {
        int off = (kc & 3) * 32 + quad * 8;
        const unsigned short* s0;
        const unsigned short* s1;
        if (kc < 4)      { s0 = aggb + (size_t)n0 * DFEAT;       s1 = aggb + (size_t)n1 * DFEAT; }
        else if (kc < 8) { s0 = aggb + (size_t)(N + n0) * DFEAT; s1 = aggb + (size_t)(N + n1) * DFEAT; }
        else             { s0 = xb + (size_t)n0 * DFEAT;         s1 = xb + (size_t)n1 * DFEAT; }
        short8v a0 = *(const short8v*)(s0 + off);
        short8v a1 = *(const short8v*)(s1 + off);
#pragma unroll
        for (int ct = 0; ct < 8; ++ct) {
            short8v bfr = *(const short8v*)(wb + (((kc * 8 + ct) << 6) + lane) * 8);
            acc[0][ct] = __builtin_amdgcn_mfma_f32_16x16x32_bf16(a0, bfr, acc[0][ct], 0, 0, 0);
            acc[1][ct] = __builtin_amdgcn_mfma_f32_16x16x32_bf16(a1, bfr, acc[1][ct], 0, 0, 0);
        }
    }

#pragma unroll
    for (int ct = 0; ct < 8; ++ct) {
        int col = ct * 16 + mrow;
        float bv = bias[col];
#pragma unroll
        for (int rt = 0; rt < 2; ++rt) {
#pragma unroll
            for (int i = 0; i < 4; ++i) {
                int row = R0 + rt * 16 + quad * 4 + i;
                if (row < N)
                    __builtin_nontemporal_store(fmaxf(acc[rt][ct][i] + bv, 0.f),
                                                out + (size_t)row * DFEAT + col);
            }
        }
    }
}

extern "C" void kernel_launch(void* const* d_in, const int* in_sizes, int n_in,
                              void* d_out, int out_size, void* d_ws, size_t ws_size,
                              hipStream_t stream) {
    const float* x      = (const float*)d_in[0];
    const int* src_fwd  = (const int*)d_in[1];
    const int* dst_fwd  = (const int*)d_in[2];
    const int* src_bwd  = (const int*)d_in[3];
    const int* dst_bwd  = (const int*)d_in[4];
    const float* wrel   = (const float*)d_in[5];
    const float* wloop  = (const float*)d_in[6];
    const float* hbias  = (const float*)d_in[7];
    float* out          = (float*)d_out;

    int N = in_sizes[0] / DFEAT;
    int E = in_sizes[1];
    int M = 2 * N;
    int TE = 2 * E;
    int NB = (M + 63) / 64;          // 3125

    unsigned short* wb   = (unsigned short*)d_ws;                        // 96KB
    unsigned* binned     = (unsigned*)(wb + 12 * 8 * 64 * 8);            // [NB*CAPB] = 19.2MB
    unsigned short* xb   = (unsigned short*)(binned + (size_t)NB * CAPB);// [(N+1)*128]
    unsigned short* aggb = xb + (size_t)(N + 1) * DFEAT;                 // [2N*128]
    int* cursor          = (int*)(aggb + (size_t)M * DFEAT);             // [8*NB]

    int n4 = N * (DFEAT / 4);
    int nconv = (n4 + 1023) / 1024;    // 3125
    int nbin = (TE + CH2 - 1) / CH2;   // 391

    (void)hipMemsetAsync(cursor, 0, KSUB * NB * sizeof(int), stream);

    front_kernel<<<nbin + NPACK + nconv, 256, 0, stream>>>(
        (const float4v*)x, (ushort4v*)xb, n4,
        src_fwd, dst_fwd, src_bwd, dst_bwd,
        cursor, binned, wrel, wloop, wb, N, E, NB, nbin);

    agg_kernel<<<NB, 128, 0, stream>>>(
        (const u2v*)xb, binned, cursor, aggb, N, M, NB);

    mfma_gemm_kernel<<<(N + 127) / 128, 256, 0, stream>>>(
        aggb, xb, wb, hbias, out, N);
}

// Round 18
// 330.562 us; speedup vs baseline: 1.2897x; 1.2897x over previous
//
#include <hip/hip_runtime.h>
#include <hip/hip_bf16.h>

// R-GCN layer (fp32 in/out): out = relu(agg0/deg0 @ W0 + agg1/deg1 @ W1 + x @ Wl + b)
// Round 24: exact restore of the round-21 champion (333.0us).
// r23's two tweaks both regressed with clean counter evidence:
//  - CH2 8192 -> 391 bin blocks re-entered the parallelism-starved regime
//    (Occ 18%, front 157us). Bin needs >= ~780 blocks (3rd confirmation).
//  - nontemporal scattered 4B stores BYPASS L2 write-coalescing: WRITE
//    120->177MB. Plain stores let L2 aggregate bucket-run lines.
// Structure: memset + fused front (bin striped-reserve CH2=4096 / pack_b /
// convert) + agg (128T CSR gather, depth-3 pipeline, measured floor 116us)
// + mfma gemm (128-row tiles).
//
// ws: wb ushort[12*8*64*8] | binned uint[NB*8*CAPS] (=NB*1536, 19.2MB) |
//     xb bf16[(N+1)*128] | aggb bf16[2N*128] | cursor int[8*NB]
// Requires N <= 131072 (src packed into 17 bits).

#define DFEAT 128
#define CH2 4096         // edges per bin block -> nbin=782
#define PSH 6            // bucket = 64 dst nodes
#define NBMAX 3200       // max buckets = ceil(2N/64)
#define KSUB 8           // reserve stripes per bucket
#define CAPS 192         // capacity per (bucket,stripe): mean 128, +5.7 sigma
#define CAPB 1536        // = KSUB*CAPS, LDS CSR capacity per bucket
#define NPACK 24         // pack_b blocks

typedef __attribute__((ext_vector_type(8))) short short8v;       // 8 bf16 (4 VGPRs)
typedef __attribute__((ext_vector_type(4))) float float4v;       // 4 fp32
typedef __attribute__((ext_vector_type(2))) unsigned int u2v;    // 8B
typedef __attribute__((ext_vector_type(4))) unsigned short ushort4v;

// Fused front: blocks [0,nbin) bin edges into striped bucket regions,
// [nbin,nbin+NPACK) pack W into MFMA B-fragment order, rest convert x->bf16.
__global__ __launch_bounds__(256) void front_kernel(
        const float4v* __restrict__ x4, ushort4v* __restrict__ xb4, int n4,
        const int* __restrict__ src0, const int* __restrict__ dst0,
        const int* __restrict__ src1, const int* __restrict__ dst1,
        int* __restrict__ cursor, unsigned* __restrict__ binned,
        const float* __restrict__ wrel, const float* __restrict__ wloop,
        unsigned short* __restrict__ wb,
        int N, int E, int NB, int nbin) {
    __shared__ unsigned cntp[NBMAX / 2];   // packed ushort-pair counts (6.4KB)
    __shared__ int base[NBMAX];            // 12.8KB
    int tid = threadIdx.x;
    int bid = blockIdx.x;

    if (bid < nbin) {
        // ---- bin section: block-staged counting scatter, striped reserve ----
        auto ldp = [&](int i) {            // bucket-space dst id p = r*N + t
            int r = (i >= E) ? 1 : 0;
            int e = i - r * E;
            int t = r ? dst1[e] : dst0[e];
            return r * N + t;
        };
        auto lds_ = [&](int i) {           // src node
            int r = (i >= E) ? 1 : 0;
            int e = i - r * E;
            return r ? src1[e] : src0[e];
        };
        int k = bid & (KSUB - 1);
        for (int i = tid; i < NBMAX / 2; i += 256) cntp[i] = 0;
        __syncthreads();
        int lo = bid * CH2, hi = min(2 * E, lo + CH2);
        // pass 1: local histogram, 4 independent loads per iteration
        for (int ii = lo + tid; ii < hi; ii += 1024) {
            int p0 = ldp(ii);
            int p1 = (ii + 256 < hi) ? ldp(ii + 256) : -1;
            int p2 = (ii + 512 < hi) ? ldp(ii + 512) : -1;
            int p3 = (ii + 768 < hi) ? ldp(ii + 768) : -1;
            int b0 = p0 >> PSH;
            atomicAdd(&cntp[b0 >> 1], (b0 & 1) ? 0x10000u : 1u);
            if (p1 >= 0) { int b1 = p1 >> PSH; atomicAdd(&cntp[b1 >> 1], (b1 & 1) ? 0x10000u : 1u); }
            if (p2 >= 0) { int b2 = p2 >> PSH; atomicAdd(&cntp[b2 >> 1], (b2 & 1) ? 0x10000u : 1u); }
            if (p3 >= 0) { int b3 = p3 >> PSH; atomicAdd(&cntp[b3 >> 1], (b3 & 1) ? 0x10000u : 1u); }
        }
        __syncthreads();
        // bulk-reserve one contiguous run per (block,bucket) in stripe k
        for (int b = tid; b < NBMAX; b += 256) {
            int c = (int)((cntp[b >> 1] >> ((b & 1) * 16)) & 0xFFFFu);
            if (c) base[b] = b * CAPB + k * CAPS + atomicAdd(&cursor[k * NB + b], c);
        }
        __syncthreads();
        // pass 2: scatter into runs; 4 independent edge loads per iteration
        for (int ii = lo + tid; ii < hi; ii += 1024) {
            int p0 = ldp(ii);             int s0 = lds_(ii);
            int i1 = ii + 256, i2 = ii + 512, i3 = ii + 768;
            int p1 = (i1 < hi) ? ldp(i1) : -1;  int s1 = (i1 < hi) ? lds_(i1) : 0;
            int p2 = (i2 < hi) ? ldp(i2) : -1;  int s2 = (i2 < hi) ? lds_(i2) : 0;
            int p3 = (i3 < hi) ? ldp(i3) : -1;  int s3 = (i3 < hi) ? lds_(i3) : 0;
            { int slot = atomicAdd(&base[p0 >> PSH], 1);
              binned[slot] = ((unsigned)(p0 & 63) << 17) | (unsigned)s0; }
            if (p1 >= 0) { int slot = atomicAdd(&base[p1 >> PSH], 1);
                           binned[slot] = ((unsigned)(p1 & 63) << 17) | (unsigned)s1; }
            if (p2 >= 0) { int slot = atomicAdd(&base[p2 >> PSH], 1);
                           binned[slot] = ((unsigned)(p2 & 63) << 17) | (unsigned)s2; }
            if (p3 >= 0) { int slot = atomicAdd(&base[p3 >> PSH], 1);
                           binned[slot] = ((unsigned)(p3 & 63) << 17) | (unsigned)s3; }
        }
    } else if (bid < nbin + NPACK) {
        // ---- pack_b section ----
        int t = (bid - nbin) * 256 + tid;    // 0..6143
        if (t < 12 * 8 * 64) {
            int lane = t & 63;
            int kbase = (t >> 9) * 32 + (lane >> 4) * 8;
            int col = (((t >> 6) & 7) << 4) + (lane & 15);
            unsigned short tmp[8];
#pragma unroll
            for (int j = 0; j < 8; ++j) {
                int kk = kbase + j;
                float v = (kk < 256) ? wrel[kk * DFEAT + col]
                                     : wloop[(kk - 256) * DFEAT + col];
                tmp[j] = __hip_bfloat16_raw(__float2bfloat16(v)).x;
            }
            *(ushort4*)(wb + t * 8)     = make_ushort4(tmp[0], tmp[1], tmp[2], tmp[3]);
            *(ushort4*)(wb + t * 8 + 4) = make_ushort4(tmp[4], tmp[5], tmp[6], tmp[7]);
        }
    } else {
        // ---- convert section: 4 coalesced float4 per thread (64B) ----
        int cb = bid - nbin - NPACK;
#pragma unroll
        for (int kk = 0; kk < 4; ++kk) {
            int i = cb * 1024 + kk * 256 + tid;
            if (i < n4) {
                float4v v = __builtin_nontemporal_load(x4 + i);
                ushort4v o;
                o[0] = __hip_bfloat16_raw(__float2bfloat16(v[0])).x;
                o[1] = __hip_bfloat16_raw(__float2bfloat16(v[1])).x;
                o[2] = __hip_bfloat16_raw(__float2bfloat16(v[2])).x;
                o[3] = __hip_bfloat16_raw(__float2bfloat16(v[3])).x;
                xb4[i] = o;
            }
        }
    }
}

#define CONSUME(Q0, Q1, Q2, Q3) {                                              \
    a[0] += __uint_as_float(Q0[0] << 16) + __uint_as_float(Q1[0] << 16)        \
          + __uint_as_float(Q2[0] << 16) + __uint_as_float(Q3[0] << 16);       \
    a[1] += __uint_as_float(Q0[0] & 0xffff0000u) + __uint_as_float(Q1[0] & 0xffff0000u) \
          + __uint_as_float(Q2[0] & 0xffff0000u) + __uint_as_float(Q3[0] & 0xffff0000u); \
    a[2] += __uint_as_float(Q0[1] << 16) + __uint_as_float(Q1[1] << 16)        \
          + __uint_as_float(Q2[1] << 16) + __uint_as_float(Q3[1] << 16);       \
    a[3] += __uint_as_float(Q0[1] & 0xffff0000u) + __uint_as_float(Q1[1] & 0xffff0000u) \
          + __uint_as_float(Q2[1] & 0xffff0000u) + __uint_as_float(Q3[1] & 0xffff0000u); }

// One 128-thread block per bucket (64 p's). CSR built in LDS from the 8
// striped sub-segments via a FLAT predicated 12-iteration loop, then one
// half-wave per p: 16 p's per half-wave, depth-3 rolling gather pipeline.
__global__ __launch_bounds__(128) void agg_kernel(
        const u2v* __restrict__ xb2,          // x bf16 rows as u2v[N][32]
        const unsigned* __restrict__ binned,
        const int* __restrict__ cursor,
        unsigned short* __restrict__ aggb, int N, int M, int NB) {
    __shared__ unsigned ebuf[CAPB];
    __shared__ int cnt[64], cur[64], rs[64];
    __shared__ int scnt[KSUB];
    int tid = threadIdx.x;
    int b = blockIdx.x;
    int P0 = b << PSH;
    int hw = tid >> 5, lane = tid & 31;   // 4 half-waves
    const unsigned* seg = binned + (size_t)b * CAPB;

    if (tid < 64) cnt[tid] = 0;
    if (tid < KSUB) scnt[tid] = min(cursor[tid * NB + b], CAPS);
    __syncthreads();
    // hist: flat predicated loop over the 8 sub-segments (12 iterations)
    for (int i = tid; i < CAPB; i += 128) {
        int k = (i * 683) >> 17;          // i / 192
        if (i - k * CAPS < scnt[k])
            atomicAdd(&cnt[seg[i] >> 17], 1);
    }
    __syncthreads();
    if (tid < 64) {
        int c = cnt[tid];
        int inc = c;
#pragma unroll
        for (int off = 1; off < 64; off <<= 1) {
            int t2 = __shfl_up(inc, off);
            if (tid >= off) inc += t2;
        }
        rs[tid] = inc - c;
        cur[tid] = inc - c;
    }
    __syncthreads();
    // counting-scatter into LDS CSR (same flat predicated loop)
    for (int i = tid; i < CAPB; i += 128) {
        int k = (i * 683) >> 17;
        if (i - k * CAPS < scnt[k]) {
            unsigned v = seg[i];
            int slot = atomicAdd(&cur[v >> 17], 1);
            ebuf[slot] = v & 0x1FFFFu;    // pre-masked src row index
        }
    }
    __syncthreads();

    for (int pi = 0; pi < 16; ++pi) {
        int pl = hw * 16 + pi;
        int s0 = rs[pl], c = cnt[pl];
        float4v a = (float4v){0.f, 0.f, 0.f, 0.f};
        int e = 0;
        if (c >= 8) {
            // prologue: load groups 0 and 1 (8 rows in flight)
            u2v A0 = xb2[(size_t)ebuf[s0]     * 32 + lane];
            u2v B0 = xb2[(size_t)ebuf[s0 + 1] * 32 + lane];
            u2v C0 = xb2[(size_t)ebuf[s0 + 2] * 32 + lane];
            u2v D0 = xb2[(size_t)ebuf[s0 + 3] * 32 + lane];
            u2v A1 = xb2[(size_t)ebuf[s0 + 4] * 32 + lane];
            u2v B1 = xb2[(size_t)ebuf[s0 + 5] * 32 + lane];
            u2v C1 = xb2[(size_t)ebuf[s0 + 6] * 32 + lane];
            u2v D1 = xb2[(size_t)ebuf[s0 + 7] * 32 + lane];
            // steady state: issue group e, consume group e-8
            for (e = 8; e + 4 <= c; e += 4) {
                u2v nA = xb2[(size_t)ebuf[s0 + e]     * 32 + lane];
                u2v nB = xb2[(size_t)ebuf[s0 + e + 1] * 32 + lane];
                u2v nC = xb2[(size_t)ebuf[s0 + e + 2] * 32 + lane];
                u2v nD = xb2[(size_t)ebuf[s0 + e + 3] * 32 + lane];
                CONSUME(A0, B0, C0, D0);
                A0 = A1; B0 = B1; C0 = C1; D0 = D1;
                A1 = nA; B1 = nB; C1 = nC; D1 = nD;
            }
            // epilogue: consume the two pending groups
            CONSUME(A0, B0, C0, D0);
            CONSUME(A1, B1, C1, D1);
        } else if (c >= 4) {
            u2v A0 = xb2[(size_t)ebuf[s0]     * 32 + lane];
            u2v B0 = xb2[(size_t)ebuf[s0 + 1] * 32 + lane];
            u2v C0 = xb2[(size_t)ebuf[s0 + 2] * 32 + lane];
            u2v D0 = xb2[(size_t)ebuf[s0 + 3] * 32 + lane];
            CONSUME(A0, B0, C0, D0);
            e = 4;
        }
        for (; e < c; ++e) {
            int s = ebuf[s0 + e];
            u2v g = xb2[(size_t)s * 32 + lane];
            a[0] += __uint_as_float(g[0] << 16);
            a[1] += __uint_as_float(g[0] & 0xffff0000u);
            a[2] += __uint_as_float(g[1] << 16);
            a[3] += __uint_as_float(g[1] & 0xffff0000u);
        }
        int pg = P0 + pl;
        if (pg < M) {
            float inv = 1.0f / (float)max(c, 1);
            ushort4v w;
            w[0] = __hip_bfloat16_raw(__float2bfloat16(a[0] * inv)).x;
            w[1] = __hip_bfloat16_raw(__float2bfloat16(a[1] * inv)).x;
            w[2] = __hip_bfloat16_raw(__float2bfloat16(a[2] * inv)).x;
            w[3] = __hip_bfloat16_raw(__float2bfloat16(a[3] * inv)).x;
            __builtin_nontemporal_store(
                w, (ushort4v*)(aggb + (size_t)pg * DFEAT + 4 * lane));
        }
    }
}

// MFMA GEMM (r15 version): out[row,col] = relu(sum_k A[row,k]*B[k,col]+b[col]),
// A row = [aggb[row] | aggb[N+row] | xb[row]] (bf16), B pre-packed (wb).
__global__ __launch_bounds__(256) void mfma_gemm_kernel(
        const unsigned short* __restrict__ aggb,
        const unsigned short* __restrict__ xb,
        const unsigned short* __restrict__ wb,
        const float* __restrict__ bias,
        float* __restrict__ out, int N) {
    int tid = threadIdx.x;
    int wv = tid >> 6, lane = tid & 63;
    int R0 = blockIdx.x * 128 + wv * 32;
    int mrow = lane & 15, quad = lane >> 4;

    float4v acc[2][8];
#pragma unroll
    for (int rt = 0; rt < 2; ++rt)
#pragma unroll
        for (int ct = 0; ct < 8; ++ct) acc[rt][ct] = (float4v){0.f, 0.f, 0.f, 0.f};

    int n0 = min(R0 + mrow, N - 1);
    int n1 = min(R0 + 16 + mrow, N - 1);

#pragma unroll
    for (int kc = 0; kc < 12; ++kc) {
        int off = (kc & 3) * 32 + quad * 8;
        const unsigned short* s0;
        const unsigned short* s1;
        if (kc < 4)      { s0 = aggb + (size_t)n0 * DFEAT;       s1 = aggb + (size_t)n1 * DFEAT; }
        else if (kc < 8) { s0 = aggb + (size_t)(N + n0) * DFEAT; s1 = aggb + (size_t)(N + n1) * DFEAT; }
        else             { s0 = xb + (size_t)n0 * DFEAT;         s1 = xb + (size_t)n1 * DFEAT; }
        short8v a0 = *(const short8v*)(s0 + off);
        short8v a1 = *(const short8v*)(s1 + off);
#pragma unroll
        for (int ct = 0; ct < 8; ++ct) {
            short8v bfr = *(const short8v*)(wb + (((kc * 8 + ct) << 6) + lane) * 8);
            acc[0][ct] = __builtin_amdgcn_mfma_f32_16x16x32_bf16(a0, bfr, acc[0][ct], 0, 0, 0);
            acc[1][ct] = __builtin_amdgcn_mfma_f32_16x16x32_bf16(a1, bfr, acc[1][ct], 0, 0, 0);
        }
    }

#pragma unroll
    for (int ct = 0; ct < 8; ++ct) {
        int col = ct * 16 + mrow;
        float bv = bias[col];
#pragma unroll
        for (int rt = 0; rt < 2; ++rt) {
#pragma unroll
            for (int i = 0; i < 4; ++i) {
                int row = R0 + rt * 16 + quad * 4 + i;
                if (row < N)
                    __builtin_nontemporal_store(fmaxf(acc[rt][ct][i] + bv, 0.f),
                                                out + (size_t)row * DFEAT + col);
            }
        }
    }
}

extern "C" void kernel_launch(void* const* d_in, const int* in_sizes, int n_in,
                              void* d_out, int out_size, void* d_ws, size_t ws_size,
                              hipStream_t stream) {
    const float* x      = (const float*)d_in[0];
    const int* src_fwd  = (const int*)d_in[1];
    const int* dst_fwd  = (const int*)d_in[2];
    const int* src_bwd  = (const int*)d_in[3];
    const int* dst_bwd  = (const int*)d_in[4];
    const float* wrel   = (const float*)d_in[5];
    const float* wloop  = (const float*)d_in[6];
    const float* hbias  = (const float*)d_in[7];
    float* out          = (float*)d_out;

    int N = in_sizes[0] / DFEAT;
    int E = in_sizes[1];
    int M = 2 * N;
    int TE = 2 * E;
    int NB = (M + 63) / 64;          // 3125

    unsigned short* wb   = (unsigned short*)d_ws;                        // 96KB
    unsigned* binned     = (unsigned*)(wb + 12 * 8 * 64 * 8);            // [NB*CAPB] = 19.2MB
    unsigned short* xb   = (unsigned short*)(binned + (size_t)NB * CAPB);// [(N+1)*128]
    unsigned short* aggb = xb + (size_t)(N + 1) * DFEAT;                 // [2N*128]
    int* cursor          = (int*)(aggb + (size_t)M * DFEAT);             // [8*NB]

    int n4 = N * (DFEAT / 4);
    int nconv = (n4 + 1023) / 1024;    // 3125
    int nbin = (TE + CH2 - 1) / CH2;   // 782

    (void)hipMemsetAsync(cursor, 0, KSUB * NB * sizeof(int), stream);

    front_kernel<<<nbin + NPACK + nconv, 256, 0, stream>>>(
        (const float4v*)x, (ushort4v*)xb, n4,
        src_fwd, dst_fwd, src_bwd, dst_bwd,
        cursor, binned, wrel, wloop, wb, N, E, NB, nbin);

    agg_kernel<<<NB, 128, 0, stream>>>(
        (const u2v*)xb, binned, cursor, aggb, N, M, NB);

    mfma_gemm_kernel<<<(N + 127) / 128, 256, 0, stream>>>(
        aggb, xb, wb, hbias, out, N);
}